// Round 1
// baseline (101895.447 us; speedup 1.0000x reference)
//
#include <hip/hip_runtime.h>

#define BB 256
#define TT 1024
#define HH 512

__device__ __forceinline__ float sigf(float v)   { return 1.f / (1.f + __expf(-v)); }
__device__ __forceinline__ float tanhf_(float v) { return 2.f / (1.f + __expf(-2.f * v)) - 1.f; }

// x: [B][T] -> xT: [T][B]  (so per-step x column reads are coalesced)
__global__ __launch_bounds__(256) void k_transpose_x(const float* __restrict__ x,
                                                     float* __restrict__ xT) {
    int t = blockIdx.x, b = threadIdx.x;
    xT[t * BB + b] = x[b * TT + t];
}

// h1(0) = GRUcell(x_0, h=0); zero the h2 buffer that represents h2(-1)
__global__ __launch_bounds__(256) void k_prologue(
    const float* __restrict__ xT,
    const float* __restrict__ Wih1, const float* __restrict__ bih1,
    const float* __restrict__ bhh1,
    float* __restrict__ h1T0, float* __restrict__ h2Tz)
{
    int u = blockIdx.x, b = threadIdx.x;
    float x0 = xT[b];  // t = 0 column
    float gr = x0 * Wih1[u]          + bih1[u]          + bhh1[u];
    float gz = x0 * Wih1[HH + u]     + bih1[HH + u]     + bhh1[HH + u];
    float gn = x0 * Wih1[2 * HH + u] + bih1[2 * HH + u];
    float hn = bhh1[2 * HH + u];
    float r = sigf(gr), z = sigf(gz);
    float n = tanhf_(gn + r * hn);
    h1T0[u * BB + b] = (1.f - z) * n;   // + z*0
    h2Tz[u * BB + b] = 0.f;
}

// Fused phase at time t:
//   blocks [0,256):   layer-2 cell:  h2(t) = GRU(h1(t), h2(t-1))
//   blocks [256,384): layer-1 cell:  h1(t+1) = GRU(x(t+1), h1(t))   (skipped at t=T-1)
//   block 384:        out[:, t-1] = h2(t-1) . Wout + bout            (skipped at t=0)
// All h buffers are transposed [HH][BB]; lanes index batch (coalesced),
// weight-row addresses are wave-uniform (HW broadcast / scalar loads).
__global__ __launch_bounds__(256) void k_phase(
    const float* __restrict__ xT,
    const float* __restrict__ Wih1, const float* __restrict__ Whh1,
    const float* __restrict__ bih1, const float* __restrict__ bhh1,
    const float* __restrict__ Wih2, const float* __restrict__ Whh2,
    const float* __restrict__ bih2, const float* __restrict__ bhh2,
    const float* __restrict__ Wout, const float* __restrict__ bout,
    const float* __restrict__ h1_cur, float* __restrict__ h1_next,
    const float* __restrict__ h2_prev, float* __restrict__ h2_out,
    float* __restrict__ out, int t)
{
    const int lane = threadIdx.x & 63;
    const int w    = threadIdx.x >> 6;
    const int bid  = blockIdx.x;

    if (bid < 256) {
        // ---- layer 2 at time t: each wave handles 2 units x 64 batch ----
        const int b  = (bid >> 6) * 64 + lane;   // batch
        const int ug = bid & 63;
        const int u0 = ug * 8 + w * 2;
        float acc[2][6];
        #pragma unroll
        for (int i = 0; i < 2; ++i)
            #pragma unroll
            for (int d = 0; d < 6; ++d) acc[i][d] = 0.f;
        const float* wr[2][6];
        #pragma unroll
        for (int i = 0; i < 2; ++i) {
            const int u = u0 + i;
            wr[i][0] = Wih2 + (size_t)u * HH;
            wr[i][1] = Wih2 + (size_t)(HH + u) * HH;
            wr[i][2] = Wih2 + (size_t)(2 * HH + u) * HH;
            wr[i][3] = Whh2 + (size_t)u * HH;
            wr[i][4] = Whh2 + (size_t)(HH + u) * HH;
            wr[i][5] = Whh2 + (size_t)(2 * HH + u) * HH;
        }
        for (int k = 0; k < HH; k += 4) {
            const float h1v0 = h1_cur[(k + 0) * BB + b];
            const float h1v1 = h1_cur[(k + 1) * BB + b];
            const float h1v2 = h1_cur[(k + 2) * BB + b];
            const float h1v3 = h1_cur[(k + 3) * BB + b];
            const float h2v0 = h2_prev[(k + 0) * BB + b];
            const float h2v1 = h2_prev[(k + 1) * BB + b];
            const float h2v2 = h2_prev[(k + 2) * BB + b];
            const float h2v3 = h2_prev[(k + 3) * BB + b];
            #pragma unroll
            for (int i = 0; i < 2; ++i) {
                #pragma unroll
                for (int d = 0; d < 6; ++d) {
                    const float4 wv = *(const float4*)(wr[i][d] + k);
                    if (d < 3) acc[i][d] += wv.x*h1v0 + wv.y*h1v1 + wv.z*h1v2 + wv.w*h1v3;
                    else       acc[i][d] += wv.x*h2v0 + wv.y*h2v1 + wv.z*h2v2 + wv.w*h2v3;
                }
            }
        }
        #pragma unroll
        for (int i = 0; i < 2; ++i) {
            const int u = u0 + i;
            const float gir = acc[i][0] + bih2[u];
            const float giz = acc[i][1] + bih2[HH + u];
            const float gin = acc[i][2] + bih2[2 * HH + u];
            const float ghr = acc[i][3] + bhh2[u];
            const float ghz = acc[i][4] + bhh2[HH + u];
            const float ghn = acc[i][5] + bhh2[2 * HH + u];
            const float r = sigf(gir + ghr);
            const float z = sigf(giz + ghz);
            const float n = tanhf_(gin + r * ghn);
            const float hp = h2_prev[u * BB + b];
            h2_out[u * BB + b] = (1.f - z) * n + z * hp;
        }
    } else if (bid < 384) {
        // ---- layer 1 at time t+1: each wave handles 4 units x 64 batch ----
        if (t + 1 >= TT) return;
        const int bid2 = bid - 256;
        const int b  = (bid2 >> 5) * 64 + lane;
        const int ug = bid2 & 31;
        const int u0 = ug * 16 + w * 4;
        float acc[4][3];
        #pragma unroll
        for (int i = 0; i < 4; ++i)
            #pragma unroll
            for (int d = 0; d < 3; ++d) acc[i][d] = 0.f;
        const float* wr[4][3];
        #pragma unroll
        for (int i = 0; i < 4; ++i) {
            const int u = u0 + i;
            wr[i][0] = Whh1 + (size_t)u * HH;
            wr[i][1] = Whh1 + (size_t)(HH + u) * HH;
            wr[i][2] = Whh1 + (size_t)(2 * HH + u) * HH;
        }
        for (int k = 0; k < HH; k += 4) {
            const float h1v0 = h1_cur[(k + 0) * BB + b];
            const float h1v1 = h1_cur[(k + 1) * BB + b];
            const float h1v2 = h1_cur[(k + 2) * BB + b];
            const float h1v3 = h1_cur[(k + 3) * BB + b];
            #pragma unroll
            for (int i = 0; i < 4; ++i) {
                #pragma unroll
                for (int d = 0; d < 3; ++d) {
                    const float4 wv = *(const float4*)(wr[i][d] + k);
                    acc[i][d] += wv.x*h1v0 + wv.y*h1v1 + wv.z*h1v2 + wv.w*h1v3;
                }
            }
        }
        const float xv = xT[(t + 1) * BB + b];
        #pragma unroll
        for (int i = 0; i < 4; ++i) {
            const int u = u0 + i;
            const float gir = xv * Wih1[u]          + bih1[u];
            const float giz = xv * Wih1[HH + u]     + bih1[HH + u];
            const float gin = xv * Wih1[2 * HH + u] + bih1[2 * HH + u];
            const float ghr = acc[i][0] + bhh1[u];
            const float ghz = acc[i][1] + bhh1[HH + u];
            const float ghn = acc[i][2] + bhh1[2 * HH + u];
            const float r = sigf(gir + ghr);
            const float z = sigf(giz + ghz);
            const float n = tanhf_(gin + r * ghn);
            const float hp = h1_cur[u * BB + b];
            h1_next[u * BB + b] = (1.f - z) * n + z * hp;
        }
    } else {
        // ---- output column t-1 from h2(t-1) ----
        if (t < 1) return;
        const int b = threadIdx.x;
        float s = 0.f;
        for (int k = 0; k < HH; k += 4) {
            s += h2_prev[(k + 0) * BB + b] * Wout[k + 0]
               + h2_prev[(k + 1) * BB + b] * Wout[k + 1]
               + h2_prev[(k + 2) * BB + b] * Wout[k + 2]
               + h2_prev[(k + 3) * BB + b] * Wout[k + 3];
        }
        out[b * TT + (t - 1)] = s + bout[0];
    }
}

__global__ __launch_bounds__(256) void k_out(const float* __restrict__ h2,
                                             const float* __restrict__ Wout,
                                             const float* __restrict__ bout,
                                             float* __restrict__ out, int tcol) {
    const int b = threadIdx.x;
    float s = 0.f;
    for (int k = 0; k < HH; k += 4) {
        s += h2[(k + 0) * BB + b] * Wout[k + 0]
           + h2[(k + 1) * BB + b] * Wout[k + 1]
           + h2[(k + 2) * BB + b] * Wout[k + 2]
           + h2[(k + 3) * BB + b] * Wout[k + 3];
    }
    out[b * TT + tcol] = s + bout[0];
}

extern "C" void kernel_launch(void* const* d_in, const int* in_sizes, int n_in,
                              void* d_out, int out_size, void* d_ws, size_t ws_size,
                              hipStream_t stream) {
    const float* x    = (const float*)d_in[0];
    const float* Wih1 = (const float*)d_in[1];
    const float* Whh1 = (const float*)d_in[2];
    const float* bih1 = (const float*)d_in[3];
    const float* bhh1 = (const float*)d_in[4];
    const float* Wih2 = (const float*)d_in[5];
    const float* Whh2 = (const float*)d_in[6];
    const float* bih2 = (const float*)d_in[7];
    const float* bhh2 = (const float*)d_in[8];
    const float* Wout = (const float*)d_in[9];
    const float* bout = (const float*)d_in[10];
    float* out = (float*)d_out;
    float* ws  = (float*)d_ws;

    // ws layout (floats): h1T[2] | h2T[2] | xT   -- each h buf 512*256, xT 1024*256
    float* h1T[2] = { ws,              ws + 131072 };
    float* h2T[2] = { ws + 262144,     ws + 393216 };
    float* xT     = ws + 524288;                      // 3 MB total

    k_transpose_x<<<TT, 256, 0, stream>>>(x, xT);
    k_prologue<<<HH, 256, 0, stream>>>(xT, Wih1, bih1, bhh1, h1T[0], h2T[1]);

    for (int t = 0; t < TT; ++t) {
        // h1(t) in h1T[t&1]; h1(t+1) -> h1T[(t+1)&1]
        // h2(t-1) in h2T[(t+1)&1]; h2(t) -> h2T[t&1]
        k_phase<<<385, 256, 0, stream>>>(xT, Wih1, Whh1, bih1, bhh1,
                                         Wih2, Whh2, bih2, bhh2, Wout, bout,
                                         h1T[t & 1], h1T[(t + 1) & 1],
                                         h2T[(t + 1) & 1], h2T[t & 1],
                                         out, t);
    }
    // final output column from h2(1023) which lives in h2T[1023&1] = h2T[1]
    k_out<<<1, 256, 0, stream>>>(h2T[1], Wout, bout, out, 1023);
}

// Round 2
// 61699.353 us; speedup vs baseline: 1.6515x; 1.6515x over previous
//
#include <hip/hip_runtime.h>

#define NB    256   // blocks == CUs, block i owns units {2i, 2i+1} of both layers
#define NT    832   // 13 waves: 8 layer2, 4 layer1, 1 out
#define TT    1024
#define HH    512
#define BATCH 256

__device__ __forceinline__ float sigf(float v)   { return 1.f / (1.f + __expf(-v)); }
__device__ __forceinline__ float tanhf_(float v) { return 2.f / (1.f + __expf(-2.f * v)) - 1.f; }

// Device-wide barrier: per-XCD L2s are not coherent, so arrive with agent-scope
// release RMW (writes back L2), spin on agent-scope relaxed atomic loads
// (coherent path), then acquire fence (invalidates L1/L2) before next step's reads.
__device__ __forceinline__ void gridbar(unsigned* bar, int tid, unsigned target) {
    __syncthreads();  // drains this block's vmem writes to L2
    if (tid == 0) {
        __hip_atomic_fetch_add(bar, 1u, __ATOMIC_RELEASE, __HIP_MEMORY_SCOPE_AGENT);
        while (__hip_atomic_load(bar, __ATOMIC_RELAXED, __HIP_MEMORY_SCOPE_AGENT) < target)
            __builtin_amdgcn_s_sleep(2);
        __builtin_amdgcn_fence(__ATOMIC_ACQUIRE, "agent");
    }
    __syncthreads();
}

__global__ __launch_bounds__(NT, 1) void gru_persistent(
    const float* __restrict__ x,
    const float* __restrict__ Wih1, const float* __restrict__ Whh1,
    const float* __restrict__ bih1, const float* __restrict__ bhh1,
    const float* __restrict__ Wih2, const float* __restrict__ Whh2,
    const float* __restrict__ bih2, const float* __restrict__ bhh2,
    const float* __restrict__ Wout, const float* __restrict__ bout,
    float* __restrict__ out, float* __restrict__ hws, unsigned* __restrict__ bar)
{
    __shared__ float w2[2][6][HH];  // [u_off][ih_r,ih_z,ih_n,hh_r,hh_z,hh_n][k]  24 KB
    __shared__ float w1[2][3][HH];  // [u_off][hh_r,hh_z,hh_n][k]                 12 KB

    const int tid = threadIdx.x;
    const int blk = blockIdx.x;

    float* A[2]  = { hws,           hws + 131072 };  // h1 ping-pong, [u*BATCH+b]
    float* Bf[2] = { hws + 262144,  hws + 393216 };  // h2 ping-pong

    // ---- stage this block's weights into LDS (once) ----
    for (int i = tid; i < 2 * 6 * HH; i += NT) {
        int uo = i / (6 * HH), rem = i % (6 * HH), row = rem / HH, k = rem % HH;
        int u = 2 * blk + uo;
        w2[uo][row][k] = (row < 3) ? Wih2[(size_t)(row * HH + u) * HH + k]
                                   : Whh2[(size_t)((row - 3) * HH + u) * HH + k];
    }
    for (int i = tid; i < 2 * 3 * HH; i += NT) {
        int uo = i / (3 * HH), rem = i % (3 * HH), row = rem / HH, k = rem % HH;
        int u = 2 * blk + uo;
        w1[uo][row][k] = Whh1[(size_t)(row * HH + u) * HH + k];
    }

    // ---- per-role persistent registers ----
    const int uo2 = (tid >> 8) & 1;          // layer2: unit offset (safe for all tids)
    const int b   = tid & 255;               // batch index for layer1/layer2 roles
    const int u2  = 2 * blk + uo2;

    const float br_  = bih2[u2] + bhh2[u2];
    const float bz_  = bih2[HH + u2] + bhh2[HH + u2];
    const float bin_ = bih2[2 * HH + u2];
    const float bhn_ = bhh2[2 * HH + u2];

    float wx[2][3], bi_[2][3], bh_[2][3];    // layer1 per-unit scalars
    #pragma unroll
    for (int uo = 0; uo < 2; ++uo) {
        const int u = 2 * blk + uo;
        #pragma unroll
        for (int g = 0; g < 3; ++g) {
            wx[uo][g]  = Wih1[g * HH + u];
            bi_[uo][g] = bih1[g * HH + u];
            bh_[uo][g] = bhh1[g * HH + u];
        }
    }

    // ---- prologue: h2(-1)=0 in Bf[1]; h1(0)=GRU(x_0, 0) in A[0] ----
    if (tid < 512) {
        Bf[1][u2 * BATCH + b] = 0.f;
    } else if (tid < 768) {
        const float x0 = x[b * TT + 0];
        #pragma unroll
        for (int uo = 0; uo < 2; ++uo) {
            const int u = 2 * blk + uo;
            float r = sigf(x0 * wx[uo][0] + bi_[uo][0] + bh_[uo][0]);
            float z = sigf(x0 * wx[uo][1] + bi_[uo][1] + bh_[uo][1]);
            float n = tanhf_(x0 * wx[uo][2] + bi_[uo][2] + r * bh_[uo][2]);
            A[0][u * BATCH + b] = (1.f - z) * n;
        }
    }
    unsigned ep = 1;
    gridbar(bar, tid, ep * NB);

    // ---- main recurrence ----
    for (int t = 0; t < TT; ++t) {
        if (tid < 512) {
            // layer 2 at time t: h2(t) = GRU(h1(t), h2(t-1)), one (u,b) per thread
            const float* __restrict__ h1c = A[t & 1];
            const float* __restrict__ h2p = Bf[(t + 1) & 1];
            float a0 = 0.f, a1 = 0.f, a2 = 0.f, a3 = 0.f, a4 = 0.f, a5 = 0.f;
            #pragma unroll 2
            for (int k = 0; k < HH; k += 4) {
                float p[4], q[4];
                #pragma unroll
                for (int j = 0; j < 4; ++j) {
                    p[j] = h1c[(k + j) * BATCH + b];
                    q[j] = h2p[(k + j) * BATCH + b];
                }
                const float4 wir = *(const float4*)&w2[uo2][0][k];
                const float4 wiz = *(const float4*)&w2[uo2][1][k];
                const float4 win = *(const float4*)&w2[uo2][2][k];
                const float4 whr = *(const float4*)&w2[uo2][3][k];
                const float4 whz = *(const float4*)&w2[uo2][4][k];
                const float4 whn = *(const float4*)&w2[uo2][5][k];
                a0 += wir.x*p[0] + wir.y*p[1] + wir.z*p[2] + wir.w*p[3];
                a1 += wiz.x*p[0] + wiz.y*p[1] + wiz.z*p[2] + wiz.w*p[3];
                a2 += win.x*p[0] + win.y*p[1] + win.z*p[2] + win.w*p[3];
                a3 += whr.x*q[0] + whr.y*q[1] + whr.z*q[2] + whr.w*q[3];
                a4 += whz.x*q[0] + whz.y*q[1] + whz.z*q[2] + whz.w*q[3];
                a5 += whn.x*q[0] + whn.y*q[1] + whn.z*q[2] + whn.w*q[3];
            }
            const float r = sigf(a0 + a3 + br_);
            const float z = sigf(a1 + a4 + bz_);
            const float n = tanhf_(a2 + bin_ + r * (a5 + bhn_));
            const float hp = h2p[u2 * BATCH + b];
            Bf[t & 1][u2 * BATCH + b] = (1.f - z) * n + z * hp;
        } else if (tid < 768) {
            // layer 1 at time t+1: h1(t+1) = GRU(x(t+1), h1(t)), 2 units per thread
            if (t + 1 < TT) {
                const float* __restrict__ h1c = A[t & 1];
                float c00 = 0.f, c01 = 0.f, c02 = 0.f, c10 = 0.f, c11 = 0.f, c12 = 0.f;
                #pragma unroll 2
                for (int k = 0; k < HH; k += 4) {
                    float p[4];
                    #pragma unroll
                    for (int j = 0; j < 4; ++j) p[j] = h1c[(k + j) * BATCH + b];
                    const float4 a0r = *(const float4*)&w1[0][0][k];
                    const float4 a0z = *(const float4*)&w1[0][1][k];
                    const float4 a0n = *(const float4*)&w1[0][2][k];
                    const float4 a1r = *(const float4*)&w1[1][0][k];
                    const float4 a1z = *(const float4*)&w1[1][1][k];
                    const float4 a1n = *(const float4*)&w1[1][2][k];
                    c00 += a0r.x*p[0] + a0r.y*p[1] + a0r.z*p[2] + a0r.w*p[3];
                    c01 += a0z.x*p[0] + a0z.y*p[1] + a0z.z*p[2] + a0z.w*p[3];
                    c02 += a0n.x*p[0] + a0n.y*p[1] + a0n.z*p[2] + a0n.w*p[3];
                    c10 += a1r.x*p[0] + a1r.y*p[1] + a1r.z*p[2] + a1r.w*p[3];
                    c11 += a1z.x*p[0] + a1z.y*p[1] + a1z.z*p[2] + a1z.w*p[3];
                    c12 += a1n.x*p[0] + a1n.y*p[1] + a1n.z*p[2] + a1n.w*p[3];
                }
                const float xv = x[b * TT + (t + 1)];
                float* __restrict__ An = A[(t + 1) & 1];
                {
                    const float r = sigf(xv * wx[0][0] + bi_[0][0] + c00 + bh_[0][0]);
                    const float z = sigf(xv * wx[0][1] + bi_[0][1] + c01 + bh_[0][1]);
                    const float n = tanhf_(xv * wx[0][2] + bi_[0][2] + r * (c02 + bh_[0][2]));
                    const int u = 2 * blk;
                    const float hp = h1c[u * BATCH + b];
                    An[u * BATCH + b] = (1.f - z) * n + z * hp;
                }
                {
                    const float r = sigf(xv * wx[1][0] + bi_[1][0] + c10 + bh_[1][0]);
                    const float z = sigf(xv * wx[1][1] + bi_[1][1] + c11 + bh_[1][1]);
                    const float n = tanhf_(xv * wx[1][2] + bi_[1][2] + r * (c12 + bh_[1][2]));
                    const int u = 2 * blk + 1;
                    const float hp = h1c[u * BATCH + b];
                    An[u * BATCH + b] = (1.f - z) * n + z * hp;
                }
            }
        } else {
            // out column t-1 from h2(t-1): batch = blk, one wave reduces 512 units
            if (t >= 1) {
                const float* __restrict__ h2p = Bf[(t + 1) & 1];
                const int lane = tid - 768;
                float s = 0.f;
                #pragma unroll
                for (int j = 0; j < 8; ++j) {
                    const int u = lane + 64 * j;
                    s += h2p[u * BATCH + blk] * Wout[u];
                }
                #pragma unroll
                for (int off = 32; off >= 1; off >>= 1) s += __shfl_down(s, off);
                if (lane == 0) out[blk * TT + (t - 1)] = s + bout[0];
            }
        }
        ++ep;
        gridbar(bar, tid, ep * NB);
    }

    // final output column t=1023 from h2(1023) (in Bf[(TT-1)&1] = Bf[1])
    if (tid >= 768) {
        const float* __restrict__ h2l = Bf[(TT - 1) & 1];
        const int lane = tid - 768;
        float s = 0.f;
        #pragma unroll
        for (int j = 0; j < 8; ++j) {
            const int u = lane + 64 * j;
            s += h2l[u * BATCH + blk] * Wout[u];
        }
        #pragma unroll
        for (int off = 32; off >= 1; off >>= 1) s += __shfl_down(s, off);
        if (lane == 0) out[blk * TT + (TT - 1)] = s + bout[0];
    }
}

extern "C" void kernel_launch(void* const* d_in, const int* in_sizes, int n_in,
                              void* d_out, int out_size, void* d_ws, size_t ws_size,
                              hipStream_t stream) {
    const float* x    = (const float*)d_in[0];
    const float* Wih1 = (const float*)d_in[1];
    const float* Whh1 = (const float*)d_in[2];
    const float* bih1 = (const float*)d_in[3];
    const float* bhh1 = (const float*)d_in[4];
    const float* Wih2 = (const float*)d_in[5];
    const float* Whh2 = (const float*)d_in[6];
    const float* bih2 = (const float*)d_in[7];
    const float* bhh2 = (const float*)d_in[8];
    const float* Wout = (const float*)d_in[9];
    const float* bout = (const float*)d_in[10];
    float* outp = (float*)d_out;

    float* hws = (float*)d_ws;                       // 4 x 131072 floats = 2 MB
    unsigned* bar = (unsigned*)(hws + 524288);       // barrier state after h buffers

    hipMemsetAsync((void*)bar, 0, 256, stream);

    void* args[] = { (void*)&x,
                     (void*)&Wih1, (void*)&Whh1, (void*)&bih1, (void*)&bhh1,
                     (void*)&Wih2, (void*)&Whh2, (void*)&bih2, (void*)&bhh2,
                     (void*)&Wout, (void*)&bout,
                     (void*)&outp, (void*)&hws, (void*)&bar };
    hipLaunchCooperativeKernel((void*)gru_persistent, dim3(NB), dim3(NT),
                               args, 0, stream);
}

// Round 3
// 38184.329 us; speedup vs baseline: 2.6685x; 1.6158x over previous
//
#include <hip/hip_runtime.h>

#define NB 256
#define NT 512
#define TT 1024
#define HH 512
#define BATCH 256

using v8s   = __attribute__((ext_vector_type(8))) short;
using f32x4 = __attribute__((ext_vector_type(4))) float;

// LDS layout (bytes)
#define OFF_T0   0        // 65536: l2 r|z panels [p][s][pl][lane]*16
#define OFF_T1A  65536    // 16384: l2 ni compact [s][pl][slot32]*16
#define OFF_T1B  81920    // 18432: l2 [Wout|0*7|nh] compact [s][pl][slot36]*16
#define OFF_T2   100352   // 32768: l1 r|z panels
#define OFF_T3   133120   // 16384: l1 n compact
#define OFF_ZERO 149504   // 16B zeros
#define OFF_SCR  149520   // 8192: l2 scratch [mt4][tile2][16r][16c] f32
#define OFF_SCR2 157712   // 4096: l1 scratch [mt4][16][16] f32
#define LDS_BYTES 161808

__device__ __forceinline__ float sigf(float v)   { return 1.f / (1.f + __expf(-v)); }
__device__ __forceinline__ float tanhf_(float v) { return 2.f / (1.f + __expf(-2.f * v)) - 1.f; }

__device__ __forceinline__ unsigned short bf16_rne(float f) {
    union { float f; unsigned u; } a; a.f = f;
    unsigned r = (a.u + 0x7fffu + ((a.u >> 16) & 1u)) >> 16;
    return (unsigned short)r;
}
__device__ __forceinline__ float bf16_f(unsigned short h) {
    union { unsigned u; float f; } a; a.u = ((unsigned)h) << 16; return a.f;
}
__device__ __forceinline__ f32x4 MF(v8s a, v8s b, f32x4 c) {
    return __builtin_amdgcn_mfma_f32_16x16x32_bf16(a, b, c, 0, 0, 0);
}
#define ACC4(ACC, AH, AL, BH, BL) \
    ACC = MF(AH, BH, ACC); ACC = MF(AL, BH, ACC); \
    ACC = MF(AH, BL, ACC); ACC = MF(AL, BL, ACC);

__device__ __forceinline__ void gridbar(unsigned* bar, int tid, unsigned target) {
    __syncthreads();
    if (tid == 0) {
        __hip_atomic_fetch_add(bar, 1u, __ATOMIC_RELEASE, __HIP_MEMORY_SCOPE_AGENT);
        while (__hip_atomic_load(bar, __ATOMIC_RELAXED, __HIP_MEMORY_SCOPE_AGENT) < target)
            __builtin_amdgcn_s_sleep(2);
        __builtin_amdgcn_fence(__ATOMIC_ACQUIRE, "agent");
    }
    __syncthreads();
}

// x: [B][T] -> xT: [T][B], LDS-tiled 64x64
__global__ __launch_bounds__(256) void k_transpose(const float* __restrict__ x,
                                                   float* __restrict__ xT) {
    __shared__ float tile[64][65];
    const int bt = blockIdx.x, bb = blockIdx.y;
    const int lt = threadIdx.x & 63, lb = threadIdx.x >> 6;
    #pragma unroll 4
    for (int i = 0; i < 16; ++i) {
        int row = lb + i * 4;
        tile[row][lt] = x[(size_t)(bb * 64 + row) * TT + bt * 64 + lt];
    }
    __syncthreads();
    #pragma unroll 4
    for (int i = 0; i < 16; ++i) {
        int row = lb + i * 4;
        xT[(size_t)(bt * 64 + row) * BATCH + bb * 64 + lt] = tile[lt][row];
    }
}

__global__ __launch_bounds__(NT, 1) void gru_mfma(
    const float* __restrict__ xT,
    const float* __restrict__ Wih1, const float* __restrict__ Whh1,
    const float* __restrict__ bih1, const float* __restrict__ bhh1,
    const float* __restrict__ Wih2, const float* __restrict__ Whh2,
    const float* __restrict__ bih2, const float* __restrict__ bhh2,
    const float* __restrict__ Wout, const float* __restrict__ bout,
    float* __restrict__ out,
    unsigned short* __restrict__ hws,
    unsigned* __restrict__ bar)
{
    extern __shared__ char lds_b[];
    float* ldsf = (float*)lds_b;
    const int tid = threadIdx.x, blk = blockIdx.x;
    const int bg = blk >> 6, ug = blk & 63;
    const int u0 = ug * 8;

    // h planes: [b][k] bf16, hi/lo, ping-pong (A/B)
    unsigned short* h1hiA = hws;
    unsigned short* h1hiB = hws + 131072;
    unsigned short* h1loA = hws + 262144;
    unsigned short* h1loB = hws + 393216;
    unsigned short* h2hiA = hws + 524288;
    unsigned short* h2hiB = hws + 655360;
    unsigned short* h2loA = hws + 786432;
    unsigned short* h2loB = hws + 917504;

    // ================= weight staging (once) =================
    // T0: l2 [r|z], mats ih(p0)/hh(p1): element (p, n(16), k(512))
    for (int i = tid; i < 2 * 16 * 512; i += NT) {
        int p = i >> 13, rem = i & 8191, n = rem >> 9, k = rem & 511;
        const float* W = p ? Whh2 : Wih2;
        int row = (n < 8) ? (u0 + n) : (HH + u0 + (n - 8));
        float f = W[(size_t)row * HH + k];
        unsigned short hi = bf16_rne(f);
        unsigned short lo = bf16_rne(f - bf16_f(hi));
        int lane = ((k >> 3) & 3) * 16 + n, s = k >> 5, j = k & 7;
        int base = OFF_T0 + p * 32768 + s * 2048 + lane * 16 + j * 2;
        *(unsigned short*)(lds_b + base)        = hi;
        *(unsigned short*)(lds_b + base + 1024) = lo;
    }
    // T1a: l2 ni = Wih2 n-gate, cols 0..7 compact
    for (int i = tid; i < 8 * 512; i += NT) {
        int n = i >> 9, k = i & 511;
        float f = Wih2[(size_t)(2 * HH + u0 + n) * HH + k];
        unsigned short hi = bf16_rne(f);
        unsigned short lo = bf16_rne(f - bf16_f(hi));
        int g = (k >> 3) & 3, s = k >> 5, j = k & 7;
        int base = OFF_T1A + s * 1024 + (g * 8 + n) * 16 + j * 2;
        *(unsigned short*)(lds_b + base)       = hi;
        *(unsigned short*)(lds_b + base + 512) = lo;
    }
    // T1b col0: Wout
    for (int k = tid; k < 512; k += NT) {
        float f = Wout[k];
        unsigned short hi = bf16_rne(f);
        unsigned short lo = bf16_rne(f - bf16_f(hi));
        int g = (k >> 3) & 3, s = k >> 5, j = k & 7;
        int base = OFF_T1B + s * 1152 + (g * 9) * 16 + j * 2;
        *(unsigned short*)(lds_b + base)       = hi;
        *(unsigned short*)(lds_b + base + 576) = lo;
    }
    // T1b cols 8..15: Whh2 n-gate
    for (int i = tid; i < 8 * 512; i += NT) {
        int n = i >> 9, k = i & 511;
        float f = Whh2[(size_t)(2 * HH + u0 + n) * HH + k];
        unsigned short hi = bf16_rne(f);
        unsigned short lo = bf16_rne(f - bf16_f(hi));
        int g = (k >> 3) & 3, s = k >> 5, j = k & 7;
        int base = OFF_T1B + s * 1152 + (g * 9 + 1 + n) * 16 + j * 2;
        *(unsigned short*)(lds_b + base)       = hi;
        *(unsigned short*)(lds_b + base + 576) = lo;
    }
    // T2: l1 [r|z] = Whh1 r,z
    for (int i = tid; i < 16 * 512; i += NT) {
        int n = i >> 9, k = i & 511;
        int row = (n < 8) ? (u0 + n) : (HH + u0 + (n - 8));
        float f = Whh1[(size_t)row * HH + k];
        unsigned short hi = bf16_rne(f);
        unsigned short lo = bf16_rne(f - bf16_f(hi));
        int lane = ((k >> 3) & 3) * 16 + n, s = k >> 5, j = k & 7;
        int base = OFF_T2 + s * 2048 + lane * 16 + j * 2;
        *(unsigned short*)(lds_b + base)        = hi;
        *(unsigned short*)(lds_b + base + 1024) = lo;
    }
    // T3: l1 n = Whh1 n-gate, compact
    for (int i = tid; i < 8 * 512; i += NT) {
        int n = i >> 9, k = i & 511;
        float f = Whh1[(size_t)(2 * HH + u0 + n) * HH + k];
        unsigned short hi = bf16_rne(f);
        unsigned short lo = bf16_rne(f - bf16_f(hi));
        int g = (k >> 3) & 3, s = k >> 5, j = k & 7;
        int base = OFF_T3 + s * 1024 + (g * 8 + n) * 16 + j * 2;
        *(unsigned short*)(lds_b + base)       = hi;
        *(unsigned short*)(lds_b + base + 512) = lo;
    }
    if (tid < 4) ((unsigned*)(lds_b + OFF_ZERO))[tid] = 0;

    // ================= h-plane prologue =================
    for (int i = tid; i < 512; i += NT) {
        int bo = i >> 3, n = i & 7;
        int b = bg * 64 + bo, u = u0 + n;
        h2hiB[(size_t)b * HH + u] = 0; h2loB[(size_t)b * HH + u] = 0;
        float x0 = xT[b];
        float r = sigf(x0 * Wih1[u] + bih1[u] + bhh1[u]);
        float z = sigf(x0 * Wih1[HH + u] + bih1[HH + u] + bhh1[HH + u]);
        float nn = tanhf_(x0 * Wih1[2 * HH + u] + bih1[2 * HH + u] + r * bhh1[2 * HH + u]);
        float h = (1.f - z) * nn;
        unsigned short hi = bf16_rne(h);
        unsigned short lo = bf16_rne(h - bf16_f(hi));
        h1hiA[(size_t)b * HH + u] = hi; h1loA[(size_t)b * HH + u] = lo;
    }

    // ================= per-wave constants =================
    const int w = tid >> 6, lane = tid & 63;
    const int n16 = lane & 15, g4 = lane >> 4;
    const int mp = (w >> 1) & 1;
    const bool odd = (w & 1);
    const bool l2w = (w < 4);
    const int mt0 = mp * 2, mt1 = mp * 2 + 1;
    const int arow0 = bg * 64 + mt0 * 16 + n16;
    const int arow1 = arow0 + 16;
    const int kof = g4 * 8;
    const int slotA16 = (g4 * 8 + (lane & 7)) * 16;
    const bool zlane = (n16 >= 1 && n16 <= 7);
    const int sbB = (n16 == 0) ? g4 * 144 : ((n16 >= 8) ? (g4 * 9 + 1 + (n16 - 8)) * 16 : 0);

    const int ue = u0 + (lane & 7);
    float br_ = 0, bz_ = 0, bin_ = 0, bhn_ = 0;
    float wxr = 0, wxz = 0, wxn = 0, bir = 0, biz = 0, bin1 = 0, bhr = 0, bhz = 0, bhn1 = 0;
    if (l2w && !odd) {
        br_  = bih2[ue] + bhh2[ue];
        bz_  = bih2[HH + ue] + bhh2[HH + ue];
        bin_ = bih2[2 * HH + ue];
        bhn_ = bhh2[2 * HH + ue];
    }
    if (!l2w && !odd) {
        wxr = Wih1[ue]; wxz = Wih1[HH + ue]; wxn = Wih1[2 * HH + ue];
        bir = bih1[ue]; biz = bih1[HH + ue]; bin1 = bih1[2 * HH + ue];
        bhr = bhh1[ue]; bhz = bhh1[HH + ue]; bhn1 = bhh1[2 * HH + ue];
    }
    const float boutv = bout[0];

    unsigned ep = 1;
    gridbar(bar, tid, ep * NB);

    // ================= main recurrence =================
    for (int t = 0; t <= TT; ++t) {
        const unsigned short* h1h = (t & 1) ? h1hiB : h1hiA;  // h1(t)
        const unsigned short* h1l = (t & 1) ? h1loB : h1loA;
        const unsigned short* h2h = (t & 1) ? h2hiA : h2hiB;  // h2(t-1)
        const unsigned short* h2l = (t & 1) ? h2loA : h2loB;

        f32x4 acc0 = {0.f, 0.f, 0.f, 0.f}, acc1 = {0.f, 0.f, 0.f, 0.f};
        f32x4 acc2 = {0.f, 0.f, 0.f, 0.f}, acc3 = {0.f, 0.f, 0.f, 0.f};

        if (l2w && !odd) {
            // -------- T0 wave: l2 r|z, passes ih(A=h1) + hh(A=h2) --------
            #pragma unroll
            for (int p = 0; p < 2; ++p) {
                const unsigned short* Ah = p ? h2h : h1h;
                const unsigned short* Al = p ? h2l : h1l;
                const char* bb = lds_b + OFF_T0 + p * 32768 + lane * 16;
                #pragma unroll 4
                for (int s = 0; s < 16; ++s) {
                    v8s bh = *(const v8s*)(bb + s * 2048);
                    v8s bl = *(const v8s*)(bb + s * 2048 + 1024);
                    const int k = s * 32 + kof;
                    v8s a0h = *(const v8s*)(Ah + (size_t)arow0 * HH + k);
                    v8s a0l = *(const v8s*)(Al + (size_t)arow0 * HH + k);
                    v8s a1h = *(const v8s*)(Ah + (size_t)arow1 * HH + k);
                    v8s a1l = *(const v8s*)(Al + (size_t)arow1 * HH + k);
                    ACC4(acc0, a0h, a0l, bh, bl)
                    ACC4(acc1, a1h, a1l, bh, bl)
                }
            }
        } else if (l2w) {
            // -------- T1 wave: l2 ni (A=h1) and [out|nh] (A=h2) --------
            #pragma unroll 2
            for (int s = 0; s < 16; ++s) {
                const char* ba = lds_b + OFF_T1A + s * 1024;
                v8s bah = *(const v8s*)(ba + slotA16);
                v8s bal = *(const v8s*)(ba + 512 + slotA16);
                const char* bbp  = zlane ? (lds_b + OFF_ZERO) : (lds_b + OFF_T1B + s * 1152 + sbB);
                const char* bbp2 = zlane ? (lds_b + OFF_ZERO) : (bbp + 576);
                v8s bbh = *(const v8s*)bbp;
                v8s bbl = *(const v8s*)bbp2;
                const int k = s * 32 + kof;
                v8s a0h = *(const v8s*)(h1h + (size_t)arow0 * HH + k);
                v8s a0l = *(const v8s*)(h1l + (size_t)arow0 * HH + k);
                v8s a1h = *(const v8s*)(h1h + (size_t)arow1 * HH + k);
                v8s a1l = *(const v8s*)(h1l + (size_t)arow1 * HH + k);
                v8s c0h = *(const v8s*)(h2h + (size_t)arow0 * HH + k);
                v8s c0l = *(const v8s*)(h2l + (size_t)arow0 * HH + k);
                v8s c1h = *(const v8s*)(h2h + (size_t)arow1 * HH + k);
                v8s c1l = *(const v8s*)(h2l + (size_t)arow1 * HH + k);
                ACC4(acc0, a0h, a0l, bah, bal)
                ACC4(acc1, a1h, a1l, bah, bal)
                ACC4(acc2, c0h, c0l, bbh, bbl)
                ACC4(acc3, c1h, c1l, bbh, bbl)
            }
        } else if (!odd) {
            // -------- T2 wave: l1 r|z (A=h1) --------
            const char* bb = lds_b + OFF_T2 + lane * 16;
            #pragma unroll 4
            for (int s = 0; s < 16; ++s) {
                v8s bh = *(const v8s*)(bb + s * 2048);
                v8s bl = *(const v8s*)(bb + s * 2048 + 1024);
                const int k = s * 32 + kof;
                v8s a0h = *(const v8s*)(h1h + (size_t)arow0 * HH + k);
                v8s a0l = *(const v8s*)(h1l + (size_t)arow0 * HH + k);
                v8s a1h = *(const v8s*)(h1h + (size_t)arow1 * HH + k);
                v8s a1l = *(const v8s*)(h1l + (size_t)arow1 * HH + k);
                ACC4(acc0, a0h, a0l, bh, bl)
                ACC4(acc1, a1h, a1l, bh, bl)
            }
        } else {
            // -------- T3 wave: l1 n (A=h1) --------
            #pragma unroll 4
            for (int s = 0; s < 16; ++s) {
                const char* ba = lds_b + OFF_T3 + s * 1024;
                v8s bh = *(const v8s*)(ba + slotA16);
                v8s bl = *(const v8s*)(ba + 512 + slotA16);
                const int k = s * 32 + kof;
                v8s a0h = *(const v8s*)(h1h + (size_t)arow0 * HH + k);
                v8s a0l = *(const v8s*)(h1l + (size_t)arow0 * HH + k);
                v8s a1h = *(const v8s*)(h1h + (size_t)arow1 * HH + k);
                v8s a1l = *(const v8s*)(h1l + (size_t)arow1 * HH + k);
                ACC4(acc0, a0h, a0l, bh, bl)
                ACC4(acc1, a1h, a1l, bh, bl)
            }
        }

        // odd waves publish their accs to LDS scratch
        if (odd) {
            const int rb = g4 * 4;
            if (l2w) {
                float* sA0 = ldsf + (OFF_SCR >> 2) + (mt0 * 2 + 0) * 256;
                float* sB0 = ldsf + (OFF_SCR >> 2) + (mt0 * 2 + 1) * 256;
                float* sA1 = ldsf + (OFF_SCR >> 2) + (mt1 * 2 + 0) * 256;
                float* sB1 = ldsf + (OFF_SCR >> 2) + (mt1 * 2 + 1) * 256;
                #pragma unroll
                for (int r = 0; r < 4; ++r) {
                    sA0[(rb + r) * 16 + n16] = acc0[r];
                    sA1[(rb + r) * 16 + n16] = acc1[r];
                    sB0[(rb + r) * 16 + n16] = acc2[r];
                    sB1[(rb + r) * 16 + n16] = acc3[r];
                }
            } else {
                float* s20 = ldsf + (OFF_SCR2 >> 2) + mt0 * 256;
                float* s21 = ldsf + (OFF_SCR2 >> 2) + mt1 * 256;
                #pragma unroll
                for (int r = 0; r < 4; ++r) {
                    s20[(rb + r) * 16 + n16] = acc0[r];
                    s21[(rb + r) * 16 + n16] = acc1[r];
                }
            }
        }
        __syncthreads();

        // -------- epilogues (even waves) --------
        if (!odd && l2w) {
            unsigned short* oh = (t & 1) ? h2hiB : h2hiA;
            unsigned short* ol = (t & 1) ? h2loB : h2loA;
            #pragma unroll
            for (int mi = 0; mi < 2; ++mi) {
                const int mt = mp * 2 + mi;
                const int brow = bg * 64 + mt * 16 + g4 * 4;
                const float* sA = ldsf + (OFF_SCR >> 2) + (mt * 2 + 0) * 256;
                const float* sB = ldsf + (OFF_SCR >> 2) + (mt * 2 + 1) * 256;
                const f32x4 av = mi ? acc1 : acc0;
                #pragma unroll
                for (int r = 0; r < 4; ++r) {
                    float rv = av[r];
                    float zv = __shfl(rv, lane + 8);
                    if (n16 < 8) {
                        const int b = brow + r, u = u0 + n16;
                        float niv = sA[(g4 * 4 + r) * 16 + n16];
                        float nhv = sB[(g4 * 4 + r) * 16 + 8 + n16];
                        float rr = sigf(rv + br_);
                        float zz = sigf(zv + bz_);
                        float nn = tanhf_(niv + bin_ + rr * (nhv + bhn_));
                        float hp = bf16_f(h2h[(size_t)b * HH + u]) + bf16_f(h2l[(size_t)b * HH + u]);
                        float hn = (1.f - zz) * nn + zz * hp;
                        if (t < TT) {
                            unsigned short hi = bf16_rne(hn);
                            unsigned short lo = bf16_rne(hn - bf16_f(hi));
                            oh[(size_t)b * HH + u] = hi;
                            ol[(size_t)b * HH + u] = lo;
                        }
                        if (n16 == 0 && ug == 0 && t >= 1)
                            out[(size_t)b * TT + (t - 1)] = sB[(g4 * 4 + r) * 16] + boutv;
                    }
                }
            }
        }
        if (!odd && !l2w && (t + 1) < TT) {
            unsigned short* oh = (t & 1) ? h1hiA : h1hiB;   // h1(t+1)
            unsigned short* ol = (t & 1) ? h1loA : h1loB;
            #pragma unroll
            for (int mi = 0; mi < 2; ++mi) {
                const int mt = mp * 2 + mi;
                const int brow = bg * 64 + mt * 16 + g4 * 4;
                const float* sN = ldsf + (OFF_SCR2 >> 2) + mt * 256;
                const f32x4 av = mi ? acc1 : acc0;
                f32x4 xq = *(const f32x4*)(xT + (size_t)(t + 1) * BATCH + brow);
                #pragma unroll
                for (int r = 0; r < 4; ++r) {
                    float rv = av[r];
                    float zv = __shfl(rv, lane + 8);
                    if (n16 < 8) {
                        const int b = brow + r, u = u0 + n16;
                        float xv = xq[r];
                        float nv = sN[(g4 * 4 + r) * 16 + n16];
                        float rr = sigf(xv * wxr + bir + rv + bhr);
                        float zz = sigf(xv * wxz + biz + zv + bhz);
                        float nn = tanhf_(xv * wxn + bin1 + rr * (nv + bhn1));
                        float hp = bf16_f(h1h[(size_t)b * HH + u]) + bf16_f(h1l[(size_t)b * HH + u]);
                        float hn = (1.f - zz) * nn + zz * hp;
                        unsigned short hi = bf16_rne(hn);
                        unsigned short lo = bf16_rne(hn - bf16_f(hi));
                        oh[(size_t)b * HH + u] = hi;
                        ol[(size_t)b * HH + u] = lo;
                    }
                }
            }
        }
        ++ep;
        gridbar(bar, tid, ep * NB);
    }
}

extern "C" void kernel_launch(void* const* d_in, const int* in_sizes, int n_in,
                              void* d_out, int out_size, void* d_ws, size_t ws_size,
                              hipStream_t stream) {
    const float* x    = (const float*)d_in[0];
    const float* Wih1 = (const float*)d_in[1];
    const float* Whh1 = (const float*)d_in[2];
    const float* bih1 = (const float*)d_in[3];
    const float* bhh1 = (const float*)d_in[4];
    const float* Wih2 = (const float*)d_in[5];
    const float* Whh2 = (const float*)d_in[6];
    const float* bih2 = (const float*)d_in[7];
    const float* bhh2 = (const float*)d_in[8];
    const float* Wout = (const float*)d_in[9];
    const float* bout = (const float*)d_in[10];
    float* outp = (float*)d_out;

    unsigned short* hws = (unsigned short*)d_ws;               // 2 MB: 8 bf16 planes
    float* xT    = (float*)((char*)d_ws + 2097152);            // 1 MB
    unsigned* bar = (unsigned*)((char*)d_ws + 3145728);

    hipMemsetAsync((void*)bar, 0, 256, stream);
    k_transpose<<<dim3(16, 4), 256, 0, stream>>>(x, xT);

    hipFuncSetAttribute((const void*)gru_mfma,
                        hipFuncAttributeMaxDynamicSharedMemorySize, LDS_BYTES);

    void* args[] = { (void*)&xT,
                     (void*)&Wih1, (void*)&Whh1, (void*)&bih1, (void*)&bhh1,
                     (void*)&Wih2, (void*)&Whh2, (void*)&bih2, (void*)&bhh2,
                     (void*)&Wout, (void*)&bout,
                     (void*)&outp, (void*)&hws, (void*)&bar };
    hipLaunchCooperativeKernel((void*)gru_mfma, dim3(NB), dim3(NT),
                               args, LDS_BYTES, stream);
}

// Round 5
// 16457.903 us; speedup vs baseline: 6.1913x; 2.3201x over previous
//
#include <hip/hip_runtime.h>

#define NB 256
#define NT 512
#define TT 1024
#define HH 512
#define BATCH 256

using v8s   = __attribute__((ext_vector_type(8))) short;
using f32x4 = __attribute__((ext_vector_type(4))) float;

// ---- LDS layout (bytes) ----
#define O_RZ2I 0        // 32768: Wih2 r|z  bf16 hi+lo [s16][plane2][lane64][16B]
#define O_RZ2H 32768    // 32768: Whh2 r|z
#define O_NA   65536    // 32768: [Wih2_n(8) | Whh1_n(8)]
#define O_RZ1  98304    // 32768: Whh1 r|z
#define O_NB   131072   // 16384: Whh2_n 8 cols compact [s16][plane2][slot32][16B]
#define O_WOUT 147456   // 2048:  Wout col hi+lo [s16][g4][16B]
#define O_ZERO 149504   // 16
#define O_SCR  149520   // 12288: exchange, 3 tiles [tile3][rt4][row16][col16] f32
#define O_SCRO 161808   // 256:   ao col exchange [rt4][row16] f32
#define LDS_BYTES 162064

__device__ __forceinline__ float sigf(float v)   { return 1.f / (1.f + __expf(-v)); }
__device__ __forceinline__ float tanhf_(float v) { return 2.f / (1.f + __expf(-2.f * v)) - 1.f; }

__device__ __forceinline__ unsigned short bf16_rne(float f) {
    union { float f; unsigned u; } a; a.f = f;
    unsigned r = (a.u + 0x7fffu + ((a.u >> 16) & 1u)) >> 16;
    return (unsigned short)r;
}
__device__ __forceinline__ float bf16_f(unsigned short h) {
    union { unsigned u; float f; } a; a.u = ((unsigned)h) << 16; return a.f;
}
__device__ __forceinline__ f32x4 MF(v8s a, v8s b, f32x4 c) {
    return __builtin_amdgcn_mfma_f32_16x16x32_bf16(a, b, c, 0, 0, 0);
}

// coherent (LLC-served) loads/stores for cross-XCD h state
#define GLD(dst, addr, OFF) \
    asm volatile("global_load_dwordx4 %0, %1, off offset:" OFF " sc0 sc1" \
                 : "=v"(dst) : "v"(addr));
#define GLD8(A, p) \
    GLD(A[0], p, "0")   GLD(A[1], p, "64")  GLD(A[2], p, "128") GLD(A[3], p, "192") \
    GLD(A[4], p, "256") GLD(A[5], p, "320") GLD(A[6], p, "384") GLD(A[7], p, "448")
#define GST2(addr, val) \
    asm volatile("global_store_short %0, %1, off sc0 sc1" \
                 :: "v"(addr), "v"(val) : "memory");

// Per-bg hierarchical barrier (8 subcounters x 8 blocks -> group -> flag).
// All RELAXED atomics: h data goes sc0/sc1 (LLC-coherent); the explicit
// vmcnt(0) drain below orders each thread's inline-asm stores BEFORE the
// arrival RMW (the compiler's __syncthreads waitcnt does NOT track asm stores).
#define BSTR 512
__device__ __forceinline__ void gridbar(unsigned* barr, int bg, int ug, int tid, unsigned ep) {
    asm volatile("s_waitcnt vmcnt(0)" ::: "memory");
    __syncthreads();
    if (tid == 0) {
        unsigned* sub = barr + bg * BSTR + (ug >> 3) * 32;
        unsigned* grp = barr + bg * BSTR + 256;
        unsigned* flg = barr + bg * BSTR + 288;
        unsigned old = __hip_atomic_fetch_add(sub, 1u, __ATOMIC_RELAXED, __HIP_MEMORY_SCOPE_AGENT);
        if (old + 1 == ep * 8u) {
            unsigned g = __hip_atomic_fetch_add(grp, 1u, __ATOMIC_RELAXED, __HIP_MEMORY_SCOPE_AGENT);
            if (g + 1 == ep * 8u)
                __hip_atomic_store(flg, ep, __ATOMIC_RELAXED, __HIP_MEMORY_SCOPE_AGENT);
        }
        while (__hip_atomic_load(flg, __ATOMIC_RELAXED, __HIP_MEMORY_SCOPE_AGENT) < ep)
            __builtin_amdgcn_s_sleep(2);
    }
    __syncthreads();
}

// x: [B][T] -> xT: [T][B]
__global__ __launch_bounds__(256) void k_transpose(const float* __restrict__ x,
                                                   float* __restrict__ xT) {
    __shared__ float tile[64][65];
    const int bt = blockIdx.x, bb = blockIdx.y;
    const int lt = threadIdx.x & 63, lb = threadIdx.x >> 6;
    #pragma unroll 4
    for (int i = 0; i < 16; ++i) {
        int row = lb + i * 4;
        tile[row][lt] = x[(size_t)(bb * 64 + row) * TT + bt * 64 + lt];
    }
    __syncthreads();
    #pragma unroll 4
    for (int i = 0; i < 16; ++i) {
        int row = lb + i * 4;
        xT[(size_t)(bt * 64 + row) * BATCH + bb * 64 + lt] = tile[lt][row];
    }
}

__global__ __launch_bounds__(NT, 1) void gru_mfma(
    const float* __restrict__ xT,
    const float* __restrict__ Wih1, const float* __restrict__ Whh1,
    const float* __restrict__ bih1, const float* __restrict__ bhh1,
    const float* __restrict__ Wih2, const float* __restrict__ Whh2,
    const float* __restrict__ bih2, const float* __restrict__ bhh2,
    const float* __restrict__ Wout, const float* __restrict__ bout,
    float* __restrict__ out,
    unsigned short* __restrict__ hws,
    unsigned* __restrict__ barr)
{
    extern __shared__ char lds_b[];
    const int tid = threadIdx.x, blk = blockIdx.x;
    const int bg = blk >> 6, ug = blk & 63;
    const int u0 = ug * 8;

    // h planes [b][k] bf16 hi/lo, ping-pong
    unsigned short* h1hP[2] = { hws,          hws + 131072 };
    unsigned short* h1lP[2] = { hws + 262144, hws + 393216 };
    unsigned short* h2hP[2] = { hws + 524288, hws + 655360 };
    unsigned short* h2lP[2] = { hws + 786432, hws + 917504 };

    // ================= weight staging (bf16 hi+lo everywhere) =================
    for (int i = tid; i < 16 * 512; i += NT) {  // Wih2 r|z
        int n = i >> 9, k = i & 511;
        int row = (n < 8) ? (u0 + n) : (HH + u0 + (n - 8));
        float f = Wih2[(size_t)row * HH + k];
        unsigned short hi = bf16_rne(f), lo = bf16_rne(f - bf16_f(hi));
        int s = k >> 5, g = (k >> 3) & 3, j = k & 7, ln = g * 16 + n;
        int base = O_RZ2I + s * 2048 + ln * 16 + j * 2;
        *(unsigned short*)(lds_b + base) = hi;
        *(unsigned short*)(lds_b + base + 1024) = lo;
    }
    for (int i = tid; i < 16 * 512; i += NT) {  // Whh2 r|z
        int n = i >> 9, k = i & 511;
        int row = (n < 8) ? (u0 + n) : (HH + u0 + (n - 8));
        float f = Whh2[(size_t)row * HH + k];
        unsigned short hi = bf16_rne(f), lo = bf16_rne(f - bf16_f(hi));
        int s = k >> 5, g = (k >> 3) & 3, j = k & 7, ln = g * 16 + n;
        int base = O_RZ2H + s * 2048 + ln * 16 + j * 2;
        *(unsigned short*)(lds_b + base) = hi;
        *(unsigned short*)(lds_b + base + 1024) = lo;
    }
    for (int i = tid; i < 16 * 512; i += NT) {  // [Wih2_n | Whh1_n]
        int n = i >> 9, k = i & 511;
        float f = (n < 8) ? Wih2[(size_t)(2 * HH + u0 + n) * HH + k]
                          : Whh1[(size_t)(2 * HH + u0 + (n - 8)) * HH + k];
        unsigned short hi = bf16_rne(f), lo = bf16_rne(f - bf16_f(hi));
        int s = k >> 5, g = (k >> 3) & 3, j = k & 7, ln = g * 16 + n;
        int base = O_NA + s * 2048 + ln * 16 + j * 2;
        *(unsigned short*)(lds_b + base) = hi;
        *(unsigned short*)(lds_b + base + 1024) = lo;
    }
    for (int i = tid; i < 16 * 512; i += NT) {  // Whh1 r|z
        int n = i >> 9, k = i & 511;
        int row = (n < 8) ? (u0 + n) : (HH + u0 + (n - 8));
        float f = Whh1[(size_t)row * HH + k];
        unsigned short hi = bf16_rne(f), lo = bf16_rne(f - bf16_f(hi));
        int s = k >> 5, g = (k >> 3) & 3, j = k & 7, ln = g * 16 + n;
        int base = O_RZ1 + s * 2048 + ln * 16 + j * 2;
        *(unsigned short*)(lds_b + base) = hi;
        *(unsigned short*)(lds_b + base + 1024) = lo;
    }
    for (int i = tid; i < 8 * 512; i += NT) {   // Whh2_n compact 8 cols
        int c = i >> 9, k = i & 511;
        float f = Whh2[(size_t)(2 * HH + u0 + c) * HH + k];
        unsigned short hi = bf16_rne(f), lo = bf16_rne(f - bf16_f(hi));
        int s = k >> 5, g = (k >> 3) & 3, j = k & 7;
        int base = O_NB + s * 1024 + (g * 8 + c) * 16 + j * 2;
        *(unsigned short*)(lds_b + base) = hi;
        *(unsigned short*)(lds_b + base + 512) = lo;
    }
    for (int k = tid; k < 512; k += NT) {       // Wout col
        float f = Wout[k];
        unsigned short hi = bf16_rne(f), lo = bf16_rne(f - bf16_f(hi));
        int s = k >> 5, g = (k >> 3) & 3, j = k & 7;
        int base = O_WOUT + s * 64 + g * 16 + j * 2;
        *(unsigned short*)(lds_b + base) = hi;
        *(unsigned short*)(lds_b + base + 1024) = lo;
    }
    if (tid < 4) ((unsigned*)(lds_b + O_ZERO))[tid] = 0;

    // ================= h prologue: h2(-1)=0, h1(0)=GRU(x0, 0) =================
    {
        const int rl = tid >> 3, uo = tid & 7;
        const int b = bg * 64 + rl, u = u0 + uo;
        GST2(h2hP[1] + (size_t)b * HH + u, 0u);
        GST2(h2lP[1] + (size_t)b * HH + u, 0u);
        float x0 = xT[b];
        float r = sigf(x0 * Wih1[u] + bih1[u] + bhh1[u]);
        float z = sigf(x0 * Wih1[HH + u] + bih1[HH + u] + bhh1[HH + u]);
        float n = tanhf_(x0 * Wih1[2 * HH + u] + bih1[2 * HH + u] + r * bhh1[2 * HH + u]);
        float h = (1.f - z) * n;
        unsigned short hi = bf16_rne(h), lo = bf16_rne(h - bf16_f(hi));
        GST2(h1hP[0] + (size_t)b * HH + u, (unsigned)hi);
        GST2(h1lP[0] + (size_t)b * HH + u, (unsigned)lo);
    }

    // ================= per-wave/lane constants =================
    const int w = tid >> 6, lane = tid & 63;
    const int n16 = lane & 15, g4 = lane >> 4;
    const int rt = w & 3, kh = w >> 2;       // row-tile(16 rows), k-half(256)
    const int c = n16, cu = c & 7;
    const int u = u0 + cu;
    const int sbase = kh * 8;

    float b2rz = 0, wx1 = 0, b1rz = 0, bin2_ = 0, bhn2_ = 0, wxn1 = 0, bin1_ = 0, bhn1_ = 0;
    float hprev[4] = {0.f, 0.f, 0.f, 0.f};
    if (kh == 1) {
        b2rz = (c < 8) ? bih2[u] + bhh2[u] : bih2[HH + u] + bhh2[HH + u];
        wx1  = (c < 8) ? Wih1[u] : Wih1[HH + u];
        b1rz = (c < 8) ? bih1[u] + bhh1[u] : bih1[HH + u] + bhh1[HH + u];
        bin2_ = bih2[2 * HH + u]; bhn2_ = bhh2[2 * HH + u];
        wxn1 = Wih1[2 * HH + u]; bin1_ = bih1[2 * HH + u]; bhn1_ = bhh1[2 * HH + u];
        if (c >= 8) {  // layer-1 lanes carry h1 in regs: init to h1(0)
            #pragma unroll
            for (int j = 0; j < 4; ++j) {
                int b = bg * 64 + rt * 16 + g4 * 4 + j;
                float x0 = xT[b];
                float r = sigf(x0 * Wih1[u] + bih1[u] + bhh1[u]);
                float z = sigf(x0 * Wih1[HH + u] + bih1[HH + u] + bhh1[HH + u]);
                float nn = tanhf_(x0 * Wih1[2 * HH + u] + bih1[2 * HH + u] + r * bhh1[2 * HH + u]);
                hprev[j] = (1.f - z) * nn;
            }
        }
    }
    const float boutv = bout[0];

    // B read pointers (note the kh offsets on the compact panels — r4 bugfix)
    const char* Bi = lds_b + O_RZ2I + lane * 16;
    const char* Bh = lds_b + O_RZ2H + lane * 16;
    const char* BA = lds_b + O_NA   + lane * 16;
    const char* B1 = lds_b + O_RZ1  + lane * 16;
    const char* BBh = (n16 < 8) ? lds_b + O_NB + kh * 8192 + (g4 * 8 + n16) * 16
                                : lds_b + O_ZERO;
    const char* BBl = (n16 < 8) ? BBh + 512 : lds_b + O_ZERO;
    const int  bbs  = (n16 < 8) ? 1024 : 0;
    const char* Bo  = (n16 == 0) ? lds_b + O_WOUT + kh * 512 + g4 * 16 : lds_b + O_ZERO;
    const char* Bol = (n16 == 0) ? Bo + 1024 : lds_b + O_ZERO;
    const int  bos  = (n16 == 0) ? 64 : 0;

    float* scr = (float*)(lds_b + O_SCR);   // 3 tiles [tile][rt][row16][col16]
    float* so  = (float*)(lds_b + O_SCRO);

    unsigned ep = 1;
    gridbar(barr, bg, ug, tid, ep);

    // ================= main recurrence =================
    for (int t = 0; t <= TT; ++t) {
        const unsigned short* h1rh = h1hP[t & 1];        // h1(t)
        const unsigned short* h1rl = h1lP[t & 1];
        const unsigned short* h2rh = h2hP[(t + 1) & 1];  // h2(t-1)
        const unsigned short* h2rl = h2lP[(t + 1) & 1];
        unsigned short* h2wh = h2hP[t & 1];              // h2(t)
        unsigned short* h2wl = h2lP[t & 1];
        unsigned short* h1wh = h1hP[(t + 1) & 1];        // h1(t+1)
        unsigned short* h1wl = h1lP[(t + 1) & 1];

        const size_t aoff = ((size_t)(bg * 64 + rt * 16 + n16) * HH + (size_t)kh * 256 + g4 * 8);
        v8s A1h_[8], A1l_[8], A2h_[8], A2l_[8];
        {
            const unsigned short* p;
            p = h1rh + aoff; GLD8(A1h_, p)
            p = h1rl + aoff; GLD8(A1l_, p)
            p = h2rh + aoff; GLD8(A2h_, p)
            p = h2rl + aoff; GLD8(A2l_, p)
        }
        asm volatile("s_waitcnt vmcnt(0)" ::: "memory");
        __builtin_amdgcn_sched_barrier(0);

        f32x4 ai = {0.f,0.f,0.f,0.f}, ah = {0.f,0.f,0.f,0.f}, a1v = {0.f,0.f,0.f,0.f};
        f32x4 aA = {0.f,0.f,0.f,0.f}, aB = {0.f,0.f,0.f,0.f}, ao = {0.f,0.f,0.f,0.f};

        #pragma unroll
        for (int sl = 0; sl < 8; ++sl) {
            const int s = sbase + sl;
            v8s bh, bl;
            bh = *(const v8s*)(Bi + s * 2048); bl = *(const v8s*)(Bi + s * 2048 + 1024);
            ai = MF(A1h_[sl], bh, ai); ai = MF(A1l_[sl], bh, ai); ai = MF(A1h_[sl], bl, ai);
            bh = *(const v8s*)(Bh + s * 2048); bl = *(const v8s*)(Bh + s * 2048 + 1024);
            ah = MF(A2h_[sl], bh, ah); ah = MF(A2l_[sl], bh, ah); ah = MF(A2h_[sl], bl, ah);
            bh = *(const v8s*)(BA + s * 2048); bl = *(const v8s*)(BA + s * 2048 + 1024);
            aA = MF(A1h_[sl], bh, aA); aA = MF(A1l_[sl], bh, aA); aA = MF(A1h_[sl], bl, aA);
            bh = *(const v8s*)(B1 + s * 2048); bl = *(const v8s*)(B1 + s * 2048 + 1024);
            a1v = MF(A1h_[sl], bh, a1v); a1v = MF(A1l_[sl], bh, a1v); a1v = MF(A1h_[sl], bl, a1v);
            bh = *(const v8s*)(BBh + sl * bbs); bl = *(const v8s*)(BBl + sl * bbs);
            aB = MF(A2h_[sl], bh, aB); aB = MF(A2l_[sl], bh, aB); aB = MF(A2h_[sl], bl, aB);
            bh = *(const v8s*)(Bo + sl * bos); bl = *(const v8s*)(Bol + sl * bos);
            ao = MF(A2h_[sl], bh, ao); ao = MF(A2l_[sl], bh, ao); ao = MF(A2h_[sl], bl, ao);
        }

        // -------- exchange phase 1: (ai+ah), a1v, aA (+ ao col) --------
        if (kh == 0) {
            #pragma unroll
            for (int j = 0; j < 4; ++j) {
                const int row = g4 * 4 + j;
                scr[(0 * 4 + rt) * 256 + row * 16 + c] = ai[j] + ah[j];
                scr[(1 * 4 + rt) * 256 + row * 16 + c] = a1v[j];
                scr[(2 * 4 + rt) * 256 + row * 16 + c] = aA[j];
            }
            if (c == 0) {
                #pragma unroll
                for (int j = 0; j < 4; ++j) so[rt * 16 + g4 * 4 + j] = ao[j];
            }
        }
        __syncthreads();

        float s2v[4], zz2[4], s1v[4], rr1[4], AAv[4], xvv[4];
        if (kh == 1) {
            #pragma unroll
            for (int j = 0; j < 4; ++j) {
                const int row = g4 * 4 + j;
                const int b = bg * 64 + rt * 16 + row;
                const float AIAH = ai[j] + ah[j] + scr[(0 * 4 + rt) * 256 + row * 16 + c];
                const float A1v  = a1v[j] + scr[(1 * 4 + rt) * 256 + row * 16 + c];
                AAv[j] = aA[j] + scr[(2 * 4 + rt) * 256 + row * 16 + c];
                xvv[j] = (t + 1 < TT) ? xT[(size_t)(t + 1) * BATCH + b] : 0.f;
                s2v[j] = sigf(AIAH + b2rz);                 // r2 (c<8) / z2 (c>=8)
                s1v[j] = sigf(xvv[j] * wx1 + b1rz + A1v);   // r1 (c<8) / z1 (c>=8)
            }
            #pragma unroll
            for (int j = 0; j < 4; ++j) {
                zz2[j] = __shfl_xor(s2v[j], 8);
                rr1[j] = __shfl_xor(s1v[j], 8);
            }
        }
        __syncthreads();

        // -------- exchange phase 2: aB (reuses tile 0) --------
        if (kh == 0) {
            #pragma unroll
            for (int j = 0; j < 4; ++j) {
                const int row = g4 * 4 + j;
                scr[(0 * 4 + rt) * 256 + row * 16 + c] = aB[j];
            }
        }
        __syncthreads();

        if (kh == 1) {
            #pragma unroll
            for (int j = 0; j < 4; ++j) {
                const int row = g4 * 4 + j;
                const int b = bg * 64 + rt * 16 + row;
                if (c < 8) {
                    if (t < TT) {
                        const float ABv = aB[j] + scr[(0 * 4 + rt) * 256 + row * 16 + c];
                        float n2 = tanhf_(AAv[j] + bin2_ + s2v[j] * (ABv + bhn2_));
                        float hn = (1.f - zz2[j]) * n2 + zz2[j] * hprev[j];
                        hprev[j] = hn;
                        unsigned short hi = bf16_rne(hn), lo = bf16_rne(hn - bf16_f(hi));
                        GST2(h2wh + (size_t)b * HH + u, (unsigned)hi);
                        GST2(h2wl + (size_t)b * HH + u, (unsigned)lo);
                    }
                } else {
                    if (t + 1 < TT) {
                        float n1 = tanhf_(xvv[j] * wxn1 + bin1_ + rr1[j] * (AAv[j] + bhn1_));
                        float hn = (1.f - s1v[j]) * n1 + s1v[j] * hprev[j];
                        hprev[j] = hn;
                        unsigned short hi = bf16_rne(hn), lo = bf16_rne(hn - bf16_f(hi));
                        GST2(h1wh + (size_t)b * HH + u, (unsigned)hi);
                        GST2(h1wl + (size_t)b * HH + u, (unsigned)lo);
                    }
                }
                if (c == 0 && ug == 0 && t >= 1) {
                    float AO = ao[j] + so[rt * 16 + row];
                    out[(size_t)b * TT + (t - 1)] = AO + boutv;
                }
            }
        }
        ++ep;
        gridbar(barr, bg, ug, tid, ep);
    }
}

extern "C" void kernel_launch(void* const* d_in, const int* in_sizes, int n_in,
                              void* d_out, int out_size, void* d_ws, size_t ws_size,
                              hipStream_t stream) {
    const float* x    = (const float*)d_in[0];
    const float* Wih1 = (const float*)d_in[1];
    const float* Whh1 = (const float*)d_in[2];
    const float* bih1 = (const float*)d_in[3];
    const float* bhh1 = (const float*)d_in[4];
    const float* Wih2 = (const float*)d_in[5];
    const float* Whh2 = (const float*)d_in[6];
    const float* bih2 = (const float*)d_in[7];
    const float* bhh2 = (const float*)d_in[8];
    const float* Wout = (const float*)d_in[9];
    const float* bout = (const float*)d_in[10];
    float* outp = (float*)d_out;

    unsigned short* hws = (unsigned short*)d_ws;                 // 8 bf16 planes, 2 MB
    float* xT      = (float*)((char*)d_ws + 2097152);            // 1 MB
    unsigned* barr = (unsigned*)((char*)d_ws + 3145728);         // 8 KB

    hipMemsetAsync((void*)barr, 0, 8192, stream);
    k_transpose<<<dim3(16, 4), 256, 0, stream>>>(x, xT);

    hipFuncSetAttribute((const void*)gru_mfma,
                        hipFuncAttributeMaxDynamicSharedMemorySize, LDS_BYTES);

    void* args[] = { (void*)&xT,
                     (void*)&Wih1, (void*)&Whh1, (void*)&bih1, (void*)&bhh1,
                     (void*)&Wih2, (void*)&Whh2, (void*)&bih2, (void*)&bhh2,
                     (void*)&Wout, (void*)&bout,
                     (void*)&outp, (void*)&hws, (void*)&barr };
    hipLaunchCooperativeKernel((void*)gru_mfma, dim3(NB), dim3(NT),
                               args, LDS_BYTES, stream);
}